// Round 10
// baseline (636.586 us; speedup 1.0000x reference)
//
#include <hip/hip_runtime.h>

// SNNEncode — numerics LOCKED (r6/r8/r9 passed, absmax 2.441406e-4):
//   xw = sequential fmaf chain k=0..15, acc init 0; LIF = exact source
//   order, separate f32 roundings, fp contract(off). DO NOT REORDER.
//
// Scheduling history: r7 (per-batch global reads) died of cold-miss latency
// at prefetch distance 0; r8/r9 (LDS delivery) died of broadcast writeback
// (64-lane register writeback per ds op, ~70-110 cyc/CU-step of LDS pipe).
// This round: NO LDS AT ALL.
//  - x rows arrive via wave-uniform vector loads into 4 named register
//    buffers (2 rows each), issued 8 steps before use (counted vmcnt
//    covers L2 latency).
//  - Cold misses killed by bulk L2 pre-touch: every 256 steps, touch the
//    next 256 rows with 256-wide miss parallelism (asm keep-alive), so the
//    scan streams from the block's own XCD L2 (~2MB/XCD active window).
//  - Dot = 16 scalar v_fmac (no packing movs). No __syncthreads anywhere.
// block=128 (2 independent waves) = one b x half H; grid=256 = 1 block/CU.

constexpr int B  = 128;
constexpr int T  = 2000;
constexpr int IN = 16;
constexpr int H  = 256;
constexpr int BH = B * H;
constexpr int CH = 256;                  // touch-chunk rows

typedef float f4 __attribute__((ext_vector_type(4)));

__global__ __launch_bounds__(128, 1) void snn_stream(
    const float* __restrict__ x, const float* __restrict__ Wm,
    const float* __restrict__ tau_syn, const float* __restrict__ tau_mem,
    float* __restrict__ out)
{
#pragma clang fp contract(off)
  const int tid = threadIdx.x, bid = blockIdx.x;
  const int b = bid >> 1;
  const int h = ((bid & 1) << 7) | tid;  // 0..255

  float w[IN];
#pragma unroll
  for (int k = 0; k < IN; ++k) w[k] = Wm[h * IN + k];

  float ts = tau_syn[h]; ts = ts < 0.f ? 0.f : (ts > 1.f ? 1.f : ts);
  float tm = tau_mem[h]; tm = tm < 0.f ? 0.f : (tm > 1.f ? 1.f : tm);
  const float nts = -ts;

  const float* xb = x + (size_t)b * T * IN;
  const f4* xb4 = reinterpret_cast<const f4*>(xb);   // row r = xb4[4r..4r+3]
  float* op = out + (size_t)b * H + h;               // spikes[t,b,h]
  float vS = 0.f, iS = 0.f;

  // bulk L2 pre-touch of rows [r0, r0+CH): 1024 f4 spread over 128 lanes,
  // 8 outstanding misses per lane, 256-wide per block. Data discarded.
  auto TOUCH = [&](int r0) {
    const int lim = T * 4 - 1;
#pragma unroll
    for (int i = 0; i < 8; ++i) {
      int idx = r0 * 4 + tid + i * 128;
      idx = idx > lim ? lim : idx;
      f4 d = xb4[idx];
      asm volatile("" :: "v"(d.x), "v"(d.y), "v"(d.z), "v"(d.w));
    }
  };

  // load rows r, r+1 (clamped) into a named 8xf4 register buffer
  auto LOAD = [&](f4* buf, int r) {
    int ra = r     > T - 1 ? T - 1 : r;
    int rb = r + 1 > T - 1 ? T - 1 : r + 1;
#pragma unroll
    for (int i = 0; i < 4; ++i) {
      buf[i]     = xb4[4 * ra + i];
      buf[4 + i] = xb4[4 * rb + i];
    }
  };

  // two LIF steps consuming one buffer; LOCKED op order throughout
  auto STEP2 = [&](const f4* buf) {
#pragma unroll
    for (int rr = 0; rr < 2; ++rr) {
      float acc = 0.0f;
#pragma unroll
      for (int k = 0; k < 16; ++k)
        acc = __builtin_fmaf(buf[rr * 4 + (k >> 2)][k & 3], w[k], acc);
      const float t1 = iS - vS;
      const float t2 = tm * t1;
      const float vd = vS + t2;
      const float xm = vd - 1.0f;
      const bool  sp = xm > 0.0f;
      vS = sp ? 0.0f : vd;
      const float t3 = nts * iS;
      const float id = iS + t3;
      iS = id + acc;
      __builtin_nontemporal_store(sp ? 1.0f : 0.0f, op);
      op += BH;
    }
  };

  f4 Ab[8], Bb[8], Cb[8], Db[8];

  TOUCH(0);                              // warm rows 0..511 before first use
  TOUCH(CH);
  LOAD(Ab, 0); LOAD(Bb, 2); LOAD(Cb, 4); LOAD(Db, 6);

  for (int t0 = 0; t0 < T; t0 += 8) {    // 250 iterations, exact
    if ((t0 & (CH - 1)) == 0) TOUCH(t0 + 2 * CH);  // stay 256-512 rows ahead
    STEP2(Ab); LOAD(Ab, t0 + 8);
    STEP2(Bb); LOAD(Bb, t0 + 10);
    STEP2(Cb); LOAD(Cb, t0 + 12);
    STEP2(Db); LOAD(Db, t0 + 14);
  }

  // final state: v_f then i_f, each [B,H] f32, after spikes
  out[(size_t)T * BH + (size_t)b * H + h]      = vS;
  out[(size_t)T * BH + BH + (size_t)b * H + h] = iS;
}

extern "C" void kernel_launch(void* const* d_in, const int* in_sizes, int n_in,
                              void* d_out, int out_size, void* d_ws, size_t ws_size,
                              hipStream_t stream) {
  const float* x  = (const float*)d_in[0];
  const float* W  = (const float*)d_in[1];
  const float* ts = (const float*)d_in[2];
  const float* tm = (const float*)d_in[3];
  float* out = (float*)d_out;
  hipLaunchKernelGGL(snn_stream, dim3(B * 2), dim3(128), 0, stream,
                     x, W, ts, tm, out);
}

// Round 11
// 453.895 us; speedup vs baseline: 1.4025x; 1.4025x over previous
//
#include <hip/hip_runtime.h>

// SNNEncode — numerics LOCKED (r6/r8/r9/r10 passed, absmax 2.441406e-4):
//   xw = sequential fmaf chain k=0..15, acc init 0; LIF = exact source
//   order, separate f32 roundings, fp contract(off). DO NOT REORDER.
//
// r10 post-mortem: VGPR=20/SGPR=112 -> compiler proved x addresses
// wave-uniform and SCALARIZED the loads (s_load + lgkmcnt(0) serialization;
// r7 had the same signature). Fix this round: launder load indices through
// an asm VGPR operand (asm outputs are divergence-opaque) to force
// global_load_dwordx4 into the named f4 register buffers. Same-address
// vector loads coalesce to one line + broadcast writeback.
// Structure otherwise = r10: 4 named buffers (8-step prefetch), L2
// pre-touch 256 rows ahead (proven: FETCH 20MB), no LDS, no syncthreads.
// block=128 (2 independent waves) = one b x half H; grid=256 = 1 block/CU.

constexpr int B  = 128;
constexpr int T  = 2000;
constexpr int IN = 16;
constexpr int H  = 256;
constexpr int BH = B * H;
constexpr int CH = 256;                  // touch-chunk rows

typedef float f4 __attribute__((ext_vector_type(4)));

__global__ __launch_bounds__(128, 1) void snn_vreg(
    const float* __restrict__ x, const float* __restrict__ Wm,
    const float* __restrict__ tau_syn, const float* __restrict__ tau_mem,
    float* __restrict__ out)
{
#pragma clang fp contract(off)
  const int tid = threadIdx.x, bid = blockIdx.x;
  const int b = bid >> 1;
  const int h = ((bid & 1) << 7) | tid;  // 0..255

  float w[IN];
#pragma unroll
  for (int k = 0; k < IN; ++k) w[k] = Wm[h * IN + k];

  float ts = tau_syn[h]; ts = ts < 0.f ? 0.f : (ts > 1.f ? 1.f : ts);
  float tm = tau_mem[h]; tm = tm < 0.f ? 0.f : (tm > 1.f ? 1.f : tm);
  const float nts = -ts;

  const float* xb = x + (size_t)b * T * IN;
  const f4* xb4 = reinterpret_cast<const f4*>(xb);   // row r = xb4[4r..4r+3]
  float* op = out + (size_t)b * H + h;               // spikes[t,b,h]
  float vS = 0.f, iS = 0.f;

  // bulk L2 pre-touch of rows [r0, r0+CH): per-lane addresses (tid-based,
  // naturally divergent -> VMEM), 8 outstanding misses/lane, data discarded.
  auto TOUCH = [&](int r0) {
    const int lim = T * 4 - 1;
#pragma unroll
    for (int i = 0; i < 8; ++i) {
      int idx = r0 * 4 + tid + i * 128;
      idx = idx > lim ? lim : idx;
      f4 d = xb4[idx];
      asm volatile("" :: "v"(d.x), "v"(d.y), "v"(d.z), "v"(d.w));
    }
  };

  // load rows r, r+1 (clamped) into a named 8xf4 register buffer.
  // Index LAUNDERED through a VGPR so the compiler cannot scalarize.
  auto LOAD = [&](f4* buf, int r) {
    int ra = r     > T - 1 ? T - 1 : r;
    int rb = r + 1 > T - 1 ? T - 1 : r + 1;
    int ia = 4 * ra, ib = 4 * rb;
    asm("" : "+v"(ia));                  // divergence-opaque -> VMEM loads
    asm("" : "+v"(ib));
#pragma unroll
    for (int i = 0; i < 4; ++i) {
      buf[i]     = xb4[ia + i];
      buf[4 + i] = xb4[ib + i];
    }
  };

  // two LIF steps consuming one buffer; LOCKED op order throughout
  auto STEP2 = [&](const f4* buf) {
#pragma unroll
    for (int rr = 0; rr < 2; ++rr) {
      float acc = 0.0f;
#pragma unroll
      for (int k = 0; k < 16; ++k)
        acc = __builtin_fmaf(buf[rr * 4 + (k >> 2)][k & 3], w[k], acc);
      const float t1 = iS - vS;
      const float t2 = tm * t1;
      const float vd = vS + t2;
      const float xm = vd - 1.0f;
      const bool  sp = xm > 0.0f;
      vS = sp ? 0.0f : vd;
      const float t3 = nts * iS;
      const float id = iS + t3;
      iS = id + acc;
      __builtin_nontemporal_store(sp ? 1.0f : 0.0f, op);
      op += BH;
    }
  };

  f4 Ab[8], Bb[8], Cb[8], Db[8];

  TOUCH(0);                              // warm rows 0..511 before first use
  TOUCH(CH);
  LOAD(Ab, 0); LOAD(Bb, 2); LOAD(Cb, 4); LOAD(Db, 6);

  for (int t0 = 0; t0 < T; t0 += 8) {    // 250 iterations, exact
    if ((t0 & (CH - 1)) == 0) TOUCH(t0 + 2 * CH);  // stay 256-512 rows ahead
    STEP2(Ab); LOAD(Ab, t0 + 8);
    STEP2(Bb); LOAD(Bb, t0 + 10);
    STEP2(Cb); LOAD(Cb, t0 + 12);
    STEP2(Db); LOAD(Db, t0 + 14);
  }

  // final state: v_f then i_f, each [B,H] f32, after spikes
  out[(size_t)T * BH + (size_t)b * H + h]      = vS;
  out[(size_t)T * BH + BH + (size_t)b * H + h] = iS;
}

extern "C" void kernel_launch(void* const* d_in, const int* in_sizes, int n_in,
                              void* d_out, int out_size, void* d_ws, size_t ws_size,
                              hipStream_t stream) {
  const float* x  = (const float*)d_in[0];
  const float* W  = (const float*)d_in[1];
  const float* ts = (const float*)d_in[2];
  const float* tm = (const float*)d_in[3];
  float* out = (float*)d_out;
  hipLaunchKernelGGL(snn_vreg, dim3(B * 2), dim3(128), 0, stream,
                     x, W, ts, tm, out);
}

// Round 12
// 447.360 us; speedup vs baseline: 1.4230x; 1.0146x over previous
//
#include <hip/hip_runtime.h>

// SNNEncode — numerics LOCKED (r6/r8-r11 passed, absmax 2.441406e-4):
//   xw = sequential fmaf chain k=0..15, acc init 0; LIF = exact source
//   order, separate f32 roundings, fp contract(off). DO NOT REORDER.
//
// Lessons ledger: r7/r10 = wave-uniform loads get SCALARIZED (s_load,
// SGPR=112 signature) -> launder index through asm VGPR. r8/r9 = LDS
// delivery pays 64-lane broadcast writeback. r11 = f4 arrays passed as
// POINTERS to lambdas defeat SROA -> scratch (VGPR=84 < 160 needed).
// This round: IDENTICAL pipeline to r11 but every register slot is an
// individually NAMED f4 (macros, no arrays, no pointer params), loads via
// one laundered 32-bit byte offset per 2-row group + immediate offsets.
// 8 independent dot chains hide FMA latency; LIF (~20cyc/step) is the only
// serial part. L2 pre-touch 256-512 rows ahead (proven, FETCH ~18MB).
// block=128 (2 waves) = one b x half H; grid=256 = 1 block/CU. No LDS.

constexpr int B  = 128;
constexpr int T  = 2000;
constexpr int IN = 16;
constexpr int H  = 256;
constexpr int BH = B * H;
constexpr int CH = 256;                  // touch-chunk rows

typedef float f4 __attribute__((ext_vector_type(4)));

__global__ __launch_bounds__(128, 1) void snn_named(
    const float* __restrict__ x, const float* __restrict__ Wm,
    const float* __restrict__ tau_syn, const float* __restrict__ tau_mem,
    float* __restrict__ out)
{
#pragma clang fp contract(off)
  const int tid = threadIdx.x, bid = blockIdx.x;
  const int b = bid >> 1;
  const int h = ((bid & 1) << 7) | tid;  // 0..255

  float w[IN];                           // constant indices only -> SROA ok
#pragma unroll
  for (int k = 0; k < IN; ++k) w[k] = Wm[h * IN + k];

  float ts = tau_syn[h]; ts = ts < 0.f ? 0.f : (ts > 1.f ? 1.f : ts);
  float tm = tau_mem[h]; tm = tm < 0.f ? 0.f : (tm > 1.f ? 1.f : tm);
  const float nts = -ts;

  const char* xbc = (const char*)(x + (size_t)b * T * IN);  // byte base
  const f4*   xb4 = (const f4*)xbc;
  float* op = out + (size_t)b * H + h;   // spikes[t,b,h], stride BH
  float vS = 0.f, iS = 0.f;

  // bulk L2 pre-touch of rows [r0, r0+CH): per-lane (tid) addresses,
  // 8 outstanding misses/lane, 256-wide per block; data discarded.
  auto TOUCH = [&](int r0) {
    const int lim = T * 4 - 1;
#pragma unroll
    for (int i = 0; i < 8; ++i) {
      int idx = r0 * 4 + tid + i * 128;
      idx = idx > lim ? lim : idx;
      f4 d = xb4[idx];
      asm volatile("" :: "v"(d.x), "v"(d.y), "v"(d.z), "v"(d.w));
    }
  };

  // named register groups: 4 groups x 2 rows x 4 f4
  f4 A0, A1, A2, A3, A4, A5, A6, A7;
  f4 Bg0, Bg1, Bg2, Bg3, Bg4, Bg5, Bg6, Bg7;
  f4 C0, C1, C2, C3, C4, C5, C6, C7;
  f4 D0, D1, D2, D3, D4, D5, D6, D7;

  // load rows r, r+1 into named slots; ONE laundered 32-bit byte offset
  // (single VGPR, divergence-opaque) -> 8 global_load_dwordx4 w/ imm offs.
#define LOADG(P0_, P1_, P2_, P3_, P4_, P5_, P6_, P7_, r)                 \
  do {                                                                   \
    int ra_ = (r);                                                       \
    ra_ = ra_ > (T - 2) ? (T - 2) : ra_;                                 \
    int off_ = ra_ * (IN * 4);                                           \
    asm("" : "+v"(off_));                /* force VMEM per-lane load */  \
    const f4* q_ = (const f4*)(xbc + off_);                              \
    P0_ = q_[0]; P1_ = q_[1]; P2_ = q_[2]; P3_ = q_[3];                  \
    P4_ = q_[4]; P5_ = q_[5]; P6_ = q_[6]; P7_ = q_[7];                  \
  } while (0)

  // one LIF step (LOCKED op order) + spike store
#define LIF1(xwv)                                                        \
  do {                                                                   \
    const float t1_ = iS - vS;                                           \
    const float t2_ = tm * t1_;                                          \
    const float vd_ = vS + t2_;                                          \
    const float xm_ = vd_ - 1.0f;                                        \
    const bool  sp_ = xm_ > 0.0f;                                        \
    vS = sp_ ? 0.0f : vd_;                                               \
    const float t3_ = nts * iS;                                          \
    const float id_ = iS + t3_;                                          \
    iS = id_ + (xwv);                                                    \
    __builtin_nontemporal_store(sp_ ? 1.0f : 0.0f, op);                  \
    op += BH;                                                            \
  } while (0)

  // dot for one row held in 4 named f4 (LOCKED k-ascending fmaf chain)
#define DOT4(Q0_, Q1_, Q2_, Q3_, dst_)                                   \
  do {                                                                   \
    float a_ = 0.0f;                                                     \
    a_ = __builtin_fmaf(Q0_[0], w[0],  a_);                              \
    a_ = __builtin_fmaf(Q0_[1], w[1],  a_);                              \
    a_ = __builtin_fmaf(Q0_[2], w[2],  a_);                              \
    a_ = __builtin_fmaf(Q0_[3], w[3],  a_);                              \
    a_ = __builtin_fmaf(Q1_[0], w[4],  a_);                              \
    a_ = __builtin_fmaf(Q1_[1], w[5],  a_);                              \
    a_ = __builtin_fmaf(Q1_[2], w[6],  a_);                              \
    a_ = __builtin_fmaf(Q1_[3], w[7],  a_);                              \
    a_ = __builtin_fmaf(Q2_[0], w[8],  a_);                              \
    a_ = __builtin_fmaf(Q2_[1], w[9],  a_);                              \
    a_ = __builtin_fmaf(Q2_[2], w[10], a_);                              \
    a_ = __builtin_fmaf(Q2_[3], w[11], a_);                              \
    a_ = __builtin_fmaf(Q3_[0], w[12], a_);                              \
    a_ = __builtin_fmaf(Q3_[1], w[13], a_);                              \
    a_ = __builtin_fmaf(Q3_[2], w[14], a_);                              \
    a_ = __builtin_fmaf(Q3_[3], w[15], a_);                              \
    dst_ = a_;                                                           \
  } while (0)

  // two steps from one group: both dots first (independent chains), then
  // the two serial LIF steps
#define STEP2G(P0_, P1_, P2_, P3_, P4_, P5_, P6_, P7_)                   \
  do {                                                                   \
    float xwa_, xwb_;                                                    \
    DOT4(P0_, P1_, P2_, P3_, xwa_);                                      \
    DOT4(P4_, P5_, P6_, P7_, xwb_);                                      \
    LIF1(xwa_);                                                          \
    LIF1(xwb_);                                                          \
  } while (0)

  TOUCH(0);                              // warm rows 0..511 before first use
  TOUCH(CH);
  LOADG(A0, A1, A2, A3, A4, A5, A6, A7, 0);
  LOADG(Bg0, Bg1, Bg2, Bg3, Bg4, Bg5, Bg6, Bg7, 2);
  LOADG(C0, C1, C2, C3, C4, C5, C6, C7, 4);
  LOADG(D0, D1, D2, D3, D4, D5, D6, D7, 6);

  for (int t0 = 0; t0 < T; t0 += 8) {    // 250 iterations, exact
    if ((t0 & (CH - 1)) == 0) TOUCH(t0 + 2 * CH);  // stay 256-512 rows ahead
    STEP2G(A0, A1, A2, A3, A4, A5, A6, A7);
    LOADG(A0, A1, A2, A3, A4, A5, A6, A7, t0 + 8);
    STEP2G(Bg0, Bg1, Bg2, Bg3, Bg4, Bg5, Bg6, Bg7);
    LOADG(Bg0, Bg1, Bg2, Bg3, Bg4, Bg5, Bg6, Bg7, t0 + 10);
    STEP2G(C0, C1, C2, C3, C4, C5, C6, C7);
    LOADG(C0, C1, C2, C3, C4, C5, C6, C7, t0 + 12);
    STEP2G(D0, D1, D2, D3, D4, D5, D6, D7);
    LOADG(D0, D1, D2, D3, D4, D5, D6, D7, t0 + 14);
  }

  // final state: v_f then i_f, each [B,H] f32, after spikes
  out[(size_t)T * BH + (size_t)b * H + h]      = vS;
  out[(size_t)T * BH + BH + (size_t)b * H + h] = iS;
}

extern "C" void kernel_launch(void* const* d_in, const int* in_sizes, int n_in,
                              void* d_out, int out_size, void* d_ws, size_t ws_size,
                              hipStream_t stream) {
  const float* x  = (const float*)d_in[0];
  const float* W  = (const float*)d_in[1];
  const float* ts = (const float*)d_in[2];
  const float* tm = (const float*)d_in[3];
  float* out = (float*)d_out;
  hipLaunchKernelGGL(snn_named, dim3(B * 2), dim3(128), 0, stream,
                     x, W, ts, tm, out);
}